// Round 9
// baseline (297.662 us; speedup 1.0000x reference)
//
#include <hip/hip_runtime.h>
#include <stdint.h>

#define Tdim 128
#define Zdim 100
#define Sdim 6
#define Hdim 64
#define ZB   3200           // Z*B
#define F1   512
#define F2   128
#define Mrows (ZB * Tdim)   // 409600
#define NGRU 100            // gru-role blocks (ZB/32), 32-seq stream each
#define NMLP 1600           // mlp-role blocks: 100 gb x 8 chunks x 2 halves

typedef _Float16 f16x8 __attribute__((ext_vector_type(8)));
typedef _Float16 f16x4 __attribute__((ext_vector_type(4)));
typedef float f32x4 __attribute__((ext_vector_type(4)));
typedef float f32x2 __attribute__((ext_vector_type(2)));
typedef uint32_t u32x4 __attribute__((ext_vector_type(4)));

__device__ __forceinline__ float fast_rcp(float x) {
  return __builtin_amdgcn_rcpf(x);   // v_rcp_f32: 1 trans op, no div-fixup chain
}

// ---------------------------------------------------------------- prep
// Wf[192][96] fp16: [W_hh | W_ih | 0] per gate (K=96 fused), for the GRU.
// w1p frag-linear: [kt][ntl][kfrag][lane][8].  32768 f16.
// w2p frag-linear: [kt][nt][lane][8].          65536 f16.
// Zeroes the sync area (800 flags + 1 ticket) each iteration.
__global__ __launch_bounds__(256) void prep_kernel(
    const float* __restrict__ W_ih, const float* __restrict__ W_hh,
    const float* __restrict__ w1, const float* __restrict__ w2,
    _Float16* __restrict__ Wf, _Float16* __restrict__ w1p,
    _Float16* __restrict__ w2p, unsigned int* __restrict__ sync) {
  int i = blockIdx.x * 256 + threadIdx.x;     // grid covers 116736
  if (i < 801) sync[i] = 0u;                  // flags[800] + ticket
  if (i < 192 * 96) {
    int g = i / 96, k = i - g * 96;
    float v = (k < 64) ? W_hh[g * 64 + k] : ((k < 70) ? W_ih[g * 6 + (k - 64)] : 0.f);
    Wf[i] = (_Float16)v;
  }
  int j = i - 192 * 96;
  if (j >= 0 && j < 32768) {
    int kt = j >> 11, ntl = (j >> 10) & 1, kf = (j >> 9) & 1;
    int lane = (j >> 3) & 63, e = j & 7;
    int q = lane >> 4, c = lane & 15;
    int row = kt * 32 + ntl * 16 + c;
    int h = kf * 32 + q * 8 + e;
    w1p[j] = (_Float16)w1[row * 64 + h];
  }
  int l = j - 32768;
  if (l >= 0 && l < 65536) {
    int kt = l >> 12, nt = (l >> 9) & 7;
    int lane = (l >> 3) & 63, e = l & 7;
    int q = lane >> 4, c = lane & 15;
    int row = nt * 16 + c;
    int k = kt * 32 + q * 8 + e;
    w2p[l] = (_Float16)w2[row * 512 + k];
  }
}

// ---------------------------------------------------------------- fused GRU+MLP v4F
// 1700 blocks x 256 thr, union LDS EXACTLY 81,920 B -> 2 blocks/CU.
// GRU role (first 100 tickets, resident -> deadlock-free): v4 32-seq
// 4-wave gate-split step (R8-measured: marginal work nearly free, step
// ~1980 cy), with x STREAMED from global via 1-step register prefetch
// (v3-proven pattern) so the 64 KB xs buffer is gone and gru LDS = 73,728.
// Only ~100 CUs are shared gru+mlp; ~156 CUs run pure-mlp at full rate.
// MLP role: R1-proven 64-row-wave consumer; item = (gb, chunk, half) =
// 16 seqs x 16 timesteps = 256 rows; R6-proven flag protocol.
__global__ __launch_bounds__(256, 2) void fused_kernel(
    const float* __restrict__ x, const _Float16* __restrict__ Wf,
    const float* __restrict__ b_ih, const float* __restrict__ b_hh,
    _Float16* __restrict__ sx, const _Float16* __restrict__ w1p,
    const _Float16* __restrict__ w2p, const float* __restrict__ b1,
    const float* __restrict__ b2, const float* __restrict__ w3,
    const float* __restrict__ b3, float* __restrict__ out,
    unsigned int* __restrict__ flags, unsigned int* __restrict__ ticket) {
  union SmemU {
    unsigned int tk;                          // offset 0; dead after role pick
    struct { _Float16 hist[16][32][72]; } g;                 // 73,728 B
    struct { _Float16 w1s[32768]; _Float16 rep[4][4][512]; } m; // 81,920 B
  };
  __shared__ __align__(16) SmemU smem;        // EXACTLY 81,920 B
  const int tid = threadIdx.x;
  if (tid == 0) smem.tk = atomicAdd(ticket, 1u);
  __syncthreads();                            // tk written
  const int tk = (int)smem.tk;
  __syncthreads();                            // all read tk before union reuse

  const int lane = tid & 63;
  const int w = tid >> 6;                     // wave id 0..3
  const int c = lane & 15;                    // MFMA col
  const int q = lane >> 4;                    // quad

  if (tk < NGRU) {
    // =============================== GRU role (v4 + streamed x) =========
    const int gb = tk;                        // seqs gb*32 .. gb*32+31
    auto& hist = smem.g.hist;

    // per-lane x pointers for both column groups (x layout (b,t,z,s))
    const float* px[2];
#pragma unroll
    for (int cg = 0; cg < 2; cg++) {
      int nr = gb * 32 + cg * 16 + c;         // n = z*32 + b
      px[cg] = x + (size_t)(nr & 31) * (Tdim * Zdim * Sdim)
                 + (size_t)(nr >> 5) * Sdim;
    }

    const int gr0 = w * 16;                   // r-gate tile base
    const int gz0 = 64 + w * 16;              // z-gate tile base
    const int gn0 = 128 + w * 16;             // n-gate tile base

    // A-frags: A[m=c][k=q*8+j] per 16-gate tile, K=96 fused [h|x|0]
    f16x8 Ar[3], Az[3], Anh[2], Ani;
#pragma unroll
    for (int kf = 0; kf < 3; kf++) {
      Ar[kf] = *(const f16x8*)(Wf + (size_t)(gr0 + c) * 96 + kf * 32 + q * 8);
      Az[kf] = *(const f16x8*)(Wf + (size_t)(gz0 + c) * 96 + kf * 32 + q * 8);
    }
    Anh[0] = *(const f16x8*)(Wf + (size_t)(gn0 + c) * 96 + q * 8);
    Anh[1] = *(const f16x8*)(Wf + (size_t)(gn0 + c) * 96 + 32 + q * 8);
    Ani    = *(const f16x8*)(Wf + (size_t)(gn0 + c) * 96 + 64 + q * 8);

    // biases in D-layout (gate-local m = q*4 + r)
    f32x4 Cr, Cz, Cnh, Cni;
    {
      f32x4 bir = *(const f32x4*)(b_ih + gr0 + q * 4);
      f32x4 bhr = *(const f32x4*)(b_hh + gr0 + q * 4);
      f32x4 biz = *(const f32x4*)(b_ih + gz0 + q * 4);
      f32x4 bhz = *(const f32x4*)(b_hh + gz0 + q * 4);
#pragma unroll
      for (int r = 0; r < 4; r++) { Cr[r] = bir[r] + bhr[r]; Cz[r] = biz[r] + bhz[r]; }
      Cnh = *(const f32x4*)(b_hh + gn0 + q * 4);
      Cni = *(const f32x4*)(b_ih + gn0 + q * 4);
    }

    const uint32_t xmask = (q == 0) ? 0xffffffffu : 0u;

    f16x8 Bh0[2], Bh1[2];
    f32x4 hprev[2];
#pragma unroll
    for (int cg = 0; cg < 2; cg++) {
      Bh0[cg] = (f16x8){0, 0, 0, 0, 0, 0, 0, 0};
      Bh1[cg] = (f16x8){0, 0, 0, 0, 0, 0, 0, 0};
      hprev[cg] = (f32x4){0.f, 0.f, 0.f, 0.f};
    }

    // ---- x(0) -> seeds for t=0 (v3-proven register path, per colgroup)
    f32x2 xa[2], xb[2], xc[2];
    f32x4 Sr[2], Sz[2], Sni[2];
#pragma unroll
    for (int cg = 0; cg < 2; cg++) {
      xa[cg] = *(const f32x2*)(px[cg] + 0);
      xb[cg] = *(const f32x2*)(px[cg] + 2);
      xc[cg] = *(const f32x2*)(px[cg] + 4);
    }
#pragma unroll
    for (int cg = 0; cg < 2; cg++) {
      f16x8 Bx;
      Bx[0] = (_Float16)xa[cg][0]; Bx[1] = (_Float16)xa[cg][1];
      Bx[2] = (_Float16)xb[cg][0]; Bx[3] = (_Float16)xb[cg][1];
      Bx[4] = (_Float16)xc[cg][0]; Bx[5] = (_Float16)xc[cg][1];
      Bx[6] = (_Float16)0.f;       Bx[7] = (_Float16)0.f;
      u32x4 xv = *(u32x4*)&Bx;
      xv[0] &= xmask; xv[1] &= xmask; xv[2] &= xmask; xv[3] &= xmask;
      Bx = *(f16x8*)&xv;
      Sni[cg] = __builtin_amdgcn_mfma_f32_16x16x32_f16(Ani, Bx, Cni, 0, 0, 0);
      Sr[cg]  = __builtin_amdgcn_mfma_f32_16x16x32_f16(Ar[2], Bx, Cr, 0, 0, 0);
      Sz[cg]  = __builtin_amdgcn_mfma_f32_16x16x32_f16(Az[2], Bx, Cz, 0, 0, 0);
    }

#pragma unroll 1
    for (int tch = 0; tch < 8; tch++) {
#pragma unroll 1
      for (int tc = 0; tc < 16; tc++) {
        const int t = tch * 16 + tc;
        // ---- prefetch x(t+1) early (covered by this step's ~2000 cy)
        const int tn = (t + 1 < Tdim) ? t + 1 : Tdim - 1;
#pragma unroll
        for (int cg = 0; cg < 2; cg++) {
          const float* pn = px[cg] + (size_t)tn * (Zdim * Sdim);
          xa[cg] = *(const f32x2*)(pn + 0);
          xb[cg] = *(const f32x2*)(pn + 2);
          xc[cg] = *(const f32x2*)(pn + 4);
        }

        // ---- h-dependent MFMAs (2 dep stages), interleaved colgroups
        f32x4 Dnh[2], Dr[2], Dz[2];
#pragma unroll
        for (int cg = 0; cg < 2; cg++)
          Dnh[cg] = __builtin_amdgcn_mfma_f32_16x16x32_f16(Anh[0], Bh0[cg], Cnh, 0, 0, 0);
#pragma unroll
        for (int cg = 0; cg < 2; cg++)
          Dr[cg] = __builtin_amdgcn_mfma_f32_16x16x32_f16(Ar[0], Bh0[cg], Sr[cg], 0, 0, 0);
#pragma unroll
        for (int cg = 0; cg < 2; cg++)
          Dz[cg] = __builtin_amdgcn_mfma_f32_16x16x32_f16(Az[0], Bh0[cg], Sz[cg], 0, 0, 0);
#pragma unroll
        for (int cg = 0; cg < 2; cg++)
          Dnh[cg] = __builtin_amdgcn_mfma_f32_16x16x32_f16(Anh[1], Bh1[cg], Dnh[cg], 0, 0, 0);
#pragma unroll
        for (int cg = 0; cg < 2; cg++)
          Dr[cg] = __builtin_amdgcn_mfma_f32_16x16x32_f16(Ar[1], Bh1[cg], Dr[cg], 0, 0, 0);
#pragma unroll
        for (int cg = 0; cg < 2; cg++)
          Dz[cg] = __builtin_amdgcn_mfma_f32_16x16x32_f16(Az[1], Bh1[cg], Dz[cg], 0, 0, 0);

        // ---- activation (identical per-element math) + hist write
#pragma unroll
        for (int cg = 0; cg < 2; cg++) {
          f16x4 pk;
#pragma unroll
          for (int r = 0; r < 4; r++) {
            float er = __expf(-Dr[cg][r]);
            float rr = fast_rcp(1.f + er);    // sigmoid, no div-fixup
            float ez = __expf(-Dz[cg][r]);
            float zg = fast_rcp(1.f + ez);
            float na = Sni[cg][r] + rr * Dnh[cg][r];
            float en = __expf(2.f * na);
            float nn = 1.f - 2.f * fast_rcp(en + 1.f);  // tanh
            float hnew = nn + zg * (hprev[cg][r] - nn);
            hprev[cg][r] = hnew;
            pk[r] = (_Float16)hnew;
          }
          *(f16x4*)&hist[tc][cg * 16 + c][w * 16 + q * 4] = pk;
        }

        // ---- pre-barrier: x-projection seeds for t+1 (h-independent)
        if (t + 1 < Tdim) {
#pragma unroll
          for (int cg = 0; cg < 2; cg++) {
            f16x8 Bx;
            Bx[0] = (_Float16)xa[cg][0]; Bx[1] = (_Float16)xa[cg][1];
            Bx[2] = (_Float16)xb[cg][0]; Bx[3] = (_Float16)xb[cg][1];
            Bx[4] = (_Float16)xc[cg][0]; Bx[5] = (_Float16)xc[cg][1];
            Bx[6] = (_Float16)0.f;       Bx[7] = (_Float16)0.f;
            u32x4 xv = *(u32x4*)&Bx;
            xv[0] &= xmask; xv[1] &= xmask; xv[2] &= xmask; xv[3] &= xmask;
            Bx = *(f16x8*)&xv;
            Sni[cg] = __builtin_amdgcn_mfma_f32_16x16x32_f16(Ani, Bx, Cni, 0, 0, 0);
            Sr[cg]  = __builtin_amdgcn_mfma_f32_16x16x32_f16(Ar[2], Bx, Cr, 0, 0, 0);
            Sz[cg]  = __builtin_amdgcn_mfma_f32_16x16x32_f16(Az[2], Bx, Cz, 0, 0, 0);
          }
        }
        __syncthreads();                      // h exchange across the 4 gate waves
#pragma unroll
        for (int cg = 0; cg < 2; cg++) {
          Bh0[cg] = *(const f16x8*)&hist[tc][cg * 16 + c][q * 8];
          Bh1[cg] = *(const f16x8*)&hist[tc][cg * 16 + c][32 + q * 8];
        }
      }
      // coalesced dump of the 16-step chunk; wave w handles rows 8w..8w+7
      {
        const int t0 = tch * 16;
#pragma unroll
        for (int rr2 = 0; rr2 < 8; rr2++) {
          const int row = w * 8 + rr2;
          const int nrow = gb * 32 + row;
          _Float16* dst = sx + (size_t)nrow * Tdim * Hdim + (size_t)t0 * Hdim;
#pragma unroll
          for (int it = 0; it < 2; it++) {
            int idx = it * 64 + lane;         // 0..127
            int tcc = idx >> 3, hd8 = idx & 7;
            f16x8 vv = *(const f16x8*)&hist[tcc][row][hd8 * 8];
            *(f16x8*)(dst + tcc * 64 + hd8 * 8) = vv;
          }
        }
        __syncthreads();                      // dump drained + hist reusable
        if (tid == 0) {
          __threadfence();                    // agent-scope release of sx
          atomicAdd(&flags[gb * 8 + tch], 1u);// publish chunk
        }
      }
    }
  } else {
    // =============================== MLP role ===========================
    const int mid = tk - NGRU;                // 0..1599
    const int ch  = mid / 200;                // chunk 0..7 (early tickets first)
    const int rem = mid - ch * 200;
    const int gbm = rem % NGRU;               // producer gru block
    const int half = rem / NGRU;              // 0/1: which 16-seq half
    auto& w1s = smem.m.w1s;
    auto& rep = smem.m.rep;

    // ---- stage all of w1 into LDS while waiting (64 KB, L2-resident)
    {
      const u32x4* srcw = (const u32x4*)w1p;  // 4096 u32x4
      u32x4* dstw = (u32x4*)w1s;
#pragma unroll
      for (int i = 0; i < 16; i++)
        dstw[i * 256 + tid] = srcw[i * 256 + tid];
    }
    // ---- wait for producer chunk
    if (tid == 0) {
      while (__hip_atomic_load(&flags[gbm * 8 + ch], __ATOMIC_RELAXED,
                               __HIP_MEMORY_SCOPE_AGENT) == 0u)
        __builtin_amdgcn_s_sleep(2);
      (void)__hip_atomic_load(&flags[gbm * 8 + ch], __ATOMIC_ACQUIRE,
                              __HIP_MEMORY_SCOPE_AGENT);  // invalidate caches
    }
    __syncthreads();                          // flag seen + w1s ready

    // wave w owns 4 seqs x 16 timesteps
    const int seqB = gbm * 32 + half * 16 + w * 4;
    const size_t tB = (size_t)ch * 16;

    f16x8 Bs[4][2];
#pragma unroll
    for (int g = 0; g < 4; g++)
#pragma unroll
      for (int kk = 0; kk < 2; kk++)
        Bs[g][kk] = *(const f16x8*)(sx + ((size_t)(seqB + g) * Tdim + tB + c) * Hdim
                                    + kk * 32 + q * 8);

    f32x4 acc2[4][8];
#pragma unroll
    for (int g = 0; g < 4; g++)
#pragma unroll
      for (int nt = 0; nt < 8; nt++) acc2[g][nt] = (f32x4){0.f, 0.f, 0.f, 0.f};

    // ---- prologue: layer1 for kt=0 into rep
    {
#pragma unroll
      for (int ntl = 0; ntl < 2; ntl++) {
        f16x8 A0 = *(const f16x8*)&w1s[ntl * 1024 + lane * 8];
        f16x8 A1 = *(const f16x8*)&w1s[ntl * 1024 + 512 + lane * 8];
        f32x4 bb = *(const f32x4*)(b1 + ntl * 16 + q * 4);
        const int roff = ((2 * ntl + (q >> 1)) * 16 + c) * 8 + (q & 1) * 4;
#pragma unroll
        for (int g = 0; g < 4; g++) {
          f32x4 cc = __builtin_amdgcn_mfma_f32_16x16x32_f16(A0, Bs[g][0], bb, 0, 0, 0);
          cc = __builtin_amdgcn_mfma_f32_16x16x32_f16(A1, Bs[g][1], cc, 0, 0, 0);
          f16x4 pk;
#pragma unroll
          for (int r = 0; r < 4; r++)
            pk[r] = (_Float16)(cc[r] > 0.f ? cc[r] : 0.f);
          *(f16x4*)&rep[w][g][roff] = pk;
        }
      }
    }

#pragma unroll 1
    for (int kt = 0; kt < 16; kt++) {
      const int ktn = kt + 1;
      const bool more = (ktn < 16);
      f16x8 A2[8];                            // layer2 weights for kt (global/L2)
#pragma unroll
      for (int nt = 0; nt < 8; nt++)
        A2[nt] = *(const f16x8*)(w2p + (size_t)kt * 4096 + nt * 512 + lane * 8);
      f16x8 W0[2], W1[2];                     // layer1 weights for kt+1 (LDS)
      f32x4 bb[2];
      {
        const int kts = more ? ktn : kt;      // harmless re-read on last iter
#pragma unroll
        for (int ntl = 0; ntl < 2; ntl++) {
          W0[ntl] = *(const f16x8*)&w1s[kts * 2048 + ntl * 1024 + lane * 8];
          W1[ntl] = *(const f16x8*)&w1s[kts * 2048 + ntl * 1024 + 512 + lane * 8];
          bb[ntl] = *(const f32x4*)(b1 + kts * 32 + ntl * 16 + q * 4);
        }
      }
      f16x8 Ba[4];                            // a1(kt), written last iteration
#pragma unroll
      for (int g = 0; g < 4; g++)
        Ba[g] = *(const f16x8*)&rep[w][g][lane * 8];

      // ---- layer1 for kt+1 -> rep (WAR covered by the read->write gap)
      if (more) {
#pragma unroll
        for (int ntl = 0; ntl < 2; ntl++) {
          const int roff = ((2 * ntl + (q >> 1)) * 16 + c) * 8 + (q & 1) * 4;
#pragma unroll
          for (int g = 0; g < 4; g++) {
            f32x4 cc = __builtin_amdgcn_mfma_f32_16x16x32_f16(W0[ntl], Bs[g][0], bb[ntl], 0, 0, 0);
            cc = __builtin_amdgcn_mfma_f32_16x16x32_f16(W1[ntl], Bs[g][1], cc, 0, 0, 0);
            f16x4 pk;
#pragma unroll
            for (int r = 0; r < 4; r++)
              pk[r] = (_Float16)(cc[r] > 0.f ? cc[r] : 0.f);
            *(f16x4*)&rep[w][g][roff] = pk;
          }
        }
      }

      // ---- layer2 partial for kt
#pragma unroll
      for (int nt = 0; nt < 8; nt++)
#pragma unroll
        for (int g = 0; g < 4; g++)
          acc2[g][nt] = __builtin_amdgcn_mfma_f32_16x16x32_f16(A2[nt], Ba[g], acc2[g][nt], 0, 0, 0);
    }

    // ---- layer3: out[row] = sum relu(a2 + b2) * w3 + b3
    float part[4] = {0.f, 0.f, 0.f, 0.f};
#pragma unroll
    for (int nt = 0; nt < 8; nt++) {
      f32x4 bb = *(const f32x4*)(b2 + nt * 16 + q * 4);
      f32x4 ww = *(const f32x4*)(w3 + nt * 16 + q * 4);
#pragma unroll
      for (int g = 0; g < 4; g++) {
#pragma unroll
        for (int r = 0; r < 4; r++) {
          float v = acc2[g][nt][r] + bb[r];
          v = v > 0.f ? v : 0.f;
          part[g] = fmaf(v, ww[r], part[g]);
        }
      }
    }
#pragma unroll
    for (int g = 0; g < 4; g++) {
      part[g] += __shfl_xor(part[g], 16, 64);
      part[g] += __shfl_xor(part[g], 32, 64);
    }
    // lane (c,q): (seq seqB+q, timestep tB+c); out flat = [seq][t]
    float pv = (q == 0) ? part[0] : (q == 1) ? part[1] : (q == 2) ? part[2] : part[3];
    out[(size_t)(seqB + q) * Tdim + tB + c] = pv + b3[0];
  }
}

// ----------------------------------------------------------------
extern "C" void kernel_launch(void* const* d_in, const int* in_sizes, int n_in,
                              void* d_out, int out_size, void* d_ws, size_t ws_size,
                              hipStream_t stream) {
  const float* x    = (const float*)d_in[0];
  const float* W_ih = (const float*)d_in[1];
  const float* W_hh = (const float*)d_in[2];
  const float* b_ih = (const float*)d_in[3];
  const float* b_hh = (const float*)d_in[4];
  const float* w1   = (const float*)d_in[5];
  const float* b1   = (const float*)d_in[6];
  const float* w2   = (const float*)d_in[7];
  const float* b2   = (const float*)d_in[8];
  const float* w3   = (const float*)d_in[9];
  const float* b3   = (const float*)d_in[10];
  float* out = (float*)d_out;

  char* ws = (char*)d_ws;
  _Float16* sxf = (_Float16*)ws;                               // 52,428,800 B
  _Float16* Wf  = (_Float16*)(ws + 52428800);                  // 36,864 B
  _Float16* w1p = (_Float16*)(ws + 52428800 + 36864);          // 65,536 B
  _Float16* w2p = (_Float16*)(ws + 52428800 + 36864 + 65536);  // 131,072 B
  unsigned int* syncb = (unsigned int*)(ws + 52428800 + 36864 + 65536 + 131072); // 3,204 B
  unsigned int* flags  = syncb;        // [800]
  unsigned int* ticket = syncb + 800;  // [1]

  hipLaunchKernelGGL(prep_kernel, dim3(456), dim3(256), 0, stream,
                     W_ih, W_hh, w1, w2, Wf, w1p, w2p, syncb);
  hipLaunchKernelGGL(fused_kernel, dim3(NGRU + NMLP), dim3(256), 0, stream,
                     x, Wf, b_ih, b_hh, sxf, w1p, w2p, b1, b2, w3, b3, out,
                     flags, ticket);
}

// Round 10
// 237.972 us; speedup vs baseline: 1.2508x; 1.2508x over previous
//
#include <hip/hip_runtime.h>
#include <stdint.h>

#define Tdim 128
#define Zdim 100
#define Sdim 6
#define Hdim 64
#define ZB   3200           // Z*B
#define F1   512
#define F2   128
#define Mrows (ZB * Tdim)   // 409600
#define NGRU 100            // gru-role blocks (ZB/32)
#define NMLP 800            // mlp-role blocks (NGRU * 8 chunks)

typedef _Float16 f16x8 __attribute__((ext_vector_type(8)));
typedef _Float16 f16x4 __attribute__((ext_vector_type(4)));
typedef float f32x4 __attribute__((ext_vector_type(4)));
typedef uint32_t u32x4 __attribute__((ext_vector_type(4)));

__device__ __forceinline__ float fast_rcp(float x) {
  return __builtin_amdgcn_rcpf(x);   // v_rcp_f32: 1 trans op, no div-fixup chain
}

// ---------------------------------------------------------------- prep
// Wf[192][96] fp16: [W_hh | W_ih | 0] per gate (K=96 fused), for the GRU.
// w1p frag-linear: [kt][ntl][kfrag][lane][8].  32768 f16.
// w2p frag-linear: [kt][nt][lane][8].          65536 f16.
// Zeroes sync area: flags[800] + ticket + qhead = 802 words, each iteration.
__global__ __launch_bounds__(256) void prep_kernel(
    const float* __restrict__ W_ih, const float* __restrict__ W_hh,
    const float* __restrict__ w1, const float* __restrict__ w2,
    _Float16* __restrict__ Wf, _Float16* __restrict__ w1p,
    _Float16* __restrict__ w2p, unsigned int* __restrict__ sync) {
  int i = blockIdx.x * 256 + threadIdx.x;     // grid covers 116736
  if (i < 802) sync[i] = 0u;                  // flags[800] + ticket + qhead
  if (i < 192 * 96) {
    int g = i / 96, k = i - g * 96;
    float v = (k < 64) ? W_hh[g * 64 + k] : ((k < 70) ? W_ih[g * 6 + (k - 64)] : 0.f);
    Wf[i] = (_Float16)v;
  }
  int j = i - 192 * 96;
  if (j >= 0 && j < 32768) {
    int kt = j >> 11, ntl = (j >> 10) & 1, kf = (j >> 9) & 1;
    int lane = (j >> 3) & 63, e = j & 7;
    int q = lane >> 4, c = lane & 15;
    int row = kt * 32 + ntl * 16 + c;
    int h = kf * 32 + q * 8 + e;
    w1p[j] = (_Float16)w1[row * 64 + h];
  }
  int l = j - 32768;
  if (l >= 0 && l < 65536) {
    int kt = l >> 12, nt = (l >> 9) & 7;
    int lane = (l >> 3) & 63, e = l & 7;
    int q = lane >> 4, c = lane & 15;
    int row = nt * 16 + c;
    int k = kt * 32 + q * 8 + e;
    w2p[l] = (_Float16)w2[row * 512 + k];
  }
}

// ---------------------------------------------------------------- fused GRU+MLP (R3 + dynamic claim)
// 900 blocks x 512 threads, 1 block/CU (LDS union ~139.3 KB).
// Role by atomic ticket: first 100 started blocks take GRU (resident ->
// deadlock-free), with x PRELOADED to LDS (immune to memory contention —
// the R9 streamed-x variant proved this matters). Producer per chunk:
// dump sx -> syncthreads -> threadfence -> atomicAdd(flag).
// MLP consumers claim items DYNAMICALLY oldest-first via qhead
// (claim -> (ch,gb) ch-major), eliminating R3's static-binding spin waste:
// a consumer always takes the oldest unclaimed item, which is almost
// always already published.
__global__ __launch_bounds__(512, 2) void fused_kernel(
    const float* __restrict__ x, const _Float16* __restrict__ Wf,
    const float* __restrict__ b_ih, const float* __restrict__ b_hh,
    _Float16* __restrict__ sx, const _Float16* __restrict__ w1p,
    const _Float16* __restrict__ w2p, const float* __restrict__ b1,
    const float* __restrict__ b2, const float* __restrict__ w3,
    const float* __restrict__ b3, float* __restrict__ out,
    unsigned int* __restrict__ flags, unsigned int* __restrict__ ticket,
    unsigned int* __restrict__ qhead) {
  union SmemU {
    struct { _Float16 hist[16][32][72]; _Float16 xs[Tdim][32][8]; } g;  // 136 KB
    struct { _Float16 w1s[32768]; _Float16 rep[8][4][512]; } m;         // 96 KB
  };
  __shared__ __align__(16) SmemU smem;
  __shared__ int s_tk;
  const int tid = threadIdx.x;
  if (tid == 0) s_tk = (int)atomicAdd(ticket, 1u);
  __syncthreads();
  const int tk = s_tk;

  const int lane = tid & 63;
  const int w8 = tid >> 6;                    // wave id 0..7
  const int c = lane & 15;                    // MFMA col
  const int q = lane >> 4;                    // quad

  if (tk < NGRU) {
    // =============================== GRU role (proven R3) ===============
    const int gb = tk;
    auto& hist = smem.g.hist;
    auto& xs = smem.g.xs;
    const int s = w8 >> 2;                    // stream 0/1
    const int w = w8 & 3;                     // gate-tile wave within stream
    const int s16c = s * 16 + c;

    // ---- preload x for this block's 32 rows, pre-converted to fp16
    for (int i = 0; i < 8; i++) {
      int idx = i * 512 + tid;                // 0..4095 = (t, row)
      int t = idx >> 5, row = idx & 31;
      int nr = gb * 32 + row;                 // n = z*32 + b
      const float* p = x + (size_t)(nr & 31) * (Tdim * Zdim * Sdim)
                         + (size_t)t * (Zdim * Sdim) + (size_t)(nr >> 5) * Sdim;
      f16x8 v;
      v[0] = (_Float16)p[0]; v[1] = (_Float16)p[1]; v[2] = (_Float16)p[2];
      v[3] = (_Float16)p[3]; v[4] = (_Float16)p[4]; v[5] = (_Float16)p[5];
      v[6] = (_Float16)0.f;  v[7] = (_Float16)0.f;
      *(f16x8*)&xs[t][row][0] = v;
    }

    const int gr0 = w * 16;
    const int gz0 = 64 + w * 16;
    const int gn0 = 128 + w * 16;

    f16x8 Ar[3], Az[3], Anh[2], Ani;
#pragma unroll
    for (int kf = 0; kf < 3; kf++) {
      Ar[kf] = *(const f16x8*)(Wf + (size_t)(gr0 + c) * 96 + kf * 32 + q * 8);
      Az[kf] = *(const f16x8*)(Wf + (size_t)(gz0 + c) * 96 + kf * 32 + q * 8);
    }
    Anh[0] = *(const f16x8*)(Wf + (size_t)(gn0 + c) * 96 + q * 8);
    Anh[1] = *(const f16x8*)(Wf + (size_t)(gn0 + c) * 96 + 32 + q * 8);
    Ani    = *(const f16x8*)(Wf + (size_t)(gn0 + c) * 96 + 64 + q * 8);

    f32x4 Cr, Cz, Cnh, Cni;
    {
      f32x4 bir = *(const f32x4*)(b_ih + gr0 + q * 4);
      f32x4 bhr = *(const f32x4*)(b_hh + gr0 + q * 4);
      f32x4 biz = *(const f32x4*)(b_ih + gz0 + q * 4);
      f32x4 bhz = *(const f32x4*)(b_hh + gz0 + q * 4);
#pragma unroll
      for (int r = 0; r < 4; r++) { Cr[r] = bir[r] + bhr[r]; Cz[r] = biz[r] + bhz[r]; }
      Cnh = *(const f32x4*)(b_hh + gn0 + q * 4);
      Cni = *(const f32x4*)(b_ih + gn0 + q * 4);
    }

    const uint32_t xmask = (q == 0) ? 0xffffffffu : 0u;

    __syncthreads();                          // xs ready

    f16x8 Bh0 = {0, 0, 0, 0, 0, 0, 0, 0};
    f16x8 Bh1 = {0, 0, 0, 0, 0, 0, 0, 0};
    f32x4 hprev = {0.f, 0.f, 0.f, 0.f};

    f32x4 Dr_s, Dz_s, Dni_s;
    {
      u32x4 xv = *(const u32x4*)&xs[0][s16c][0];
      xv[0] &= xmask; xv[1] &= xmask; xv[2] &= xmask; xv[3] &= xmask;
      f16x8 Bx = *(f16x8*)&xv;
      Dni_s = __builtin_amdgcn_mfma_f32_16x16x32_f16(Ani, Bx, Cni, 0, 0, 0);
      Dr_s  = __builtin_amdgcn_mfma_f32_16x16x32_f16(Ar[2], Bx, Cr, 0, 0, 0);
      Dz_s  = __builtin_amdgcn_mfma_f32_16x16x32_f16(Az[2], Bx, Cz, 0, 0, 0);
    }

#pragma unroll 1
    for (int tch = 0; tch < 8; tch++) {
#pragma unroll 1
      for (int tc = 0; tc < 16; tc++) {
        const int t = tch * 16 + tc;
        f32x4 Dnh = __builtin_amdgcn_mfma_f32_16x16x32_f16(Anh[0], Bh0, Cnh, 0, 0, 0);
        f32x4 Dr  = __builtin_amdgcn_mfma_f32_16x16x32_f16(Ar[0], Bh0, Dr_s, 0, 0, 0);
        f32x4 Dz  = __builtin_amdgcn_mfma_f32_16x16x32_f16(Az[0], Bh0, Dz_s, 0, 0, 0);
        Dnh = __builtin_amdgcn_mfma_f32_16x16x32_f16(Anh[1], Bh1, Dnh, 0, 0, 0);
        Dr  = __builtin_amdgcn_mfma_f32_16x16x32_f16(Ar[1], Bh1, Dr, 0, 0, 0);
        Dz  = __builtin_amdgcn_mfma_f32_16x16x32_f16(Az[1], Bh1, Dz, 0, 0, 0);

        f16x4 pk;
#pragma unroll
        for (int r = 0; r < 4; r++) {
          float er = __expf(-Dr[r]);
          float rr = fast_rcp(1.f + er);
          float ez = __expf(-Dz[r]);
          float zg = fast_rcp(1.f + ez);
          float na = Dni_s[r] + rr * Dnh[r];
          float en = __expf(2.f * na);
          float nn = 1.f - 2.f * fast_rcp(en + 1.f);
          float hnew = nn + zg * (hprev[r] - nn);
          hprev[r] = hnew;
          pk[r] = (_Float16)hnew;
        }
        *(f16x4*)&hist[tc][s16c][w * 16 + q * 4] = pk;

        if (t + 1 < Tdim) {
          u32x4 xv = *(const u32x4*)&xs[t + 1][s16c][0];
          xv[0] &= xmask; xv[1] &= xmask; xv[2] &= xmask; xv[3] &= xmask;
          f16x8 Bx = *(f16x8*)&xv;
          Dni_s = __builtin_amdgcn_mfma_f32_16x16x32_f16(Ani, Bx, Cni, 0, 0, 0);
          Dr_s  = __builtin_amdgcn_mfma_f32_16x16x32_f16(Ar[2], Bx, Cr, 0, 0, 0);
          Dz_s  = __builtin_amdgcn_mfma_f32_16x16x32_f16(Az[2], Bx, Cz, 0, 0, 0);
        }
        __syncthreads();                      // h exchange across gate waves
        Bh0 = *(const f16x8*)&hist[tc][s16c][q * 8];
        Bh1 = *(const f16x8*)&hist[tc][s16c][32 + q * 8];
      }
      // coalesced dump of the 16-step chunk; wave w8 handles rows 4*w8..+3
      {
        const int t0 = tch * 16;
#pragma unroll
        for (int rr2 = 0; rr2 < 4; rr2++) {
          const int row = w8 * 4 + rr2;
          const int nrow = gb * 32 + row;
          _Float16* dst = sx + (size_t)nrow * Tdim * Hdim + (size_t)t0 * Hdim;
#pragma unroll
          for (int it = 0; it < 2; it++) {
            int idx = it * 64 + lane;         // 0..127
            int tcc = idx >> 3, hd8 = idx & 7;
            f16x8 vv = *(const f16x8*)&hist[tcc][row][hd8 * 8];
            *(f16x8*)(dst + tcc * 64 + hd8 * 8) = vv;
          }
        }
        __syncthreads();                      // dump drained (vmcnt 0) + hist reusable
        if (tid == 0) {
          __threadfence();                    // agent-scope: L2 writeback of sx
          atomicAdd(&flags[gb * 8 + tch], 1u);// publish chunk
        }
      }
    }
  } else {
    // =============================== MLP role ===========================
    // Dynamic oldest-first claim: item = (ch = claim/100, gb = claim%100).
    __syncthreads();                          // everyone has read tk
    if (tid == 0) s_tk = (int)atomicAdd(qhead, 1u);
    __syncthreads();
    const int claim = s_tk;                   // 0..799
    const int ch  = claim / NGRU;             // chunk 0..7, oldest first
    const int gbm = claim % NGRU;             // producer gru block
    auto& w1s = smem.m.w1s;
    auto& rep = smem.m.rep;

    // ---- stage all of w1 into LDS while waiting (64 KB)
    {
      const u32x4* srcw = (const u32x4*)w1p;  // 4096 u32x4
      u32x4* dstw = (u32x4*)w1s;
#pragma unroll
      for (int i = 0; i < 8; i++)
        dstw[i * 512 + tid] = srcw[i * 512 + tid];
    }
    // ---- wait for producer chunk
    if (tid == 0) {
      while (__hip_atomic_load(&flags[gbm * 8 + ch], __ATOMIC_RELAXED,
                               __HIP_MEMORY_SCOPE_AGENT) == 0u)
        __builtin_amdgcn_s_sleep(2);
      (void)__hip_atomic_load(&flags[gbm * 8 + ch], __ATOMIC_ACQUIRE,
                              __HIP_MEMORY_SCOPE_AGENT);  // inv caches
    }
    __syncthreads();                          // flag seen + w1s ready

    // wave w8 owns 4 seqs x 16 timesteps: row(g,c) = (seqB+g)*128 + ch*16 + c
    const int seqB = gbm * 32 + w8 * 4;
    const size_t tB = (size_t)ch * 16;

    f16x8 Bs[4][2];
#pragma unroll
    for (int g = 0; g < 4; g++)
#pragma unroll
      for (int kk = 0; kk < 2; kk++)
        Bs[g][kk] = *(const f16x8*)(sx + ((size_t)(seqB + g) * Tdim + tB + c) * Hdim
                                    + kk * 32 + q * 8);

    f32x4 acc2[4][8];
#pragma unroll
    for (int g = 0; g < 4; g++)
#pragma unroll
      for (int nt = 0; nt < 8; nt++) acc2[g][nt] = (f32x4){0.f, 0.f, 0.f, 0.f};

    // ---- prologue: layer1 for kt=0 into rep
    {
#pragma unroll
      for (int ntl = 0; ntl < 2; ntl++) {
        f16x8 A0 = *(const f16x8*)&w1s[ntl * 1024 + lane * 8];
        f16x8 A1 = *(const f16x8*)&w1s[ntl * 1024 + 512 + lane * 8];
        f32x4 bb = *(const f32x4*)(b1 + ntl * 16 + q * 4);
        const int roff = ((2 * ntl + (q >> 1)) * 16 + c) * 8 + (q & 1) * 4;
#pragma unroll
        for (int g = 0; g < 4; g++) {
          f32x4 cc = __builtin_amdgcn_mfma_f32_16x16x32_f16(A0, Bs[g][0], bb, 0, 0, 0);
          cc = __builtin_amdgcn_mfma_f32_16x16x32_f16(A1, Bs[g][1], cc, 0, 0, 0);
          f16x4 pk;
#pragma unroll
          for (int r = 0; r < 4; r++)
            pk[r] = (_Float16)(cc[r] > 0.f ? cc[r] : 0.f);
          *(f16x4*)&rep[w8][g][roff] = pk;
        }
      }
    }

#pragma unroll 1
    for (int kt = 0; kt < 16; kt++) {
      const int ktn = kt + 1;
      const bool more = (ktn < 16);
      f16x8 A2[8];                            // layer2 weights for kt (global/L2)
#pragma unroll
      for (int nt = 0; nt < 8; nt++)
        A2[nt] = *(const f16x8*)(w2p + (size_t)kt * 4096 + nt * 512 + lane * 8);
      f16x8 W0[2], W1[2];                     // layer1 weights for kt+1 (LDS)
      f32x4 bb[2];
      {
        const int kts = more ? ktn : kt;
#pragma unroll
        for (int ntl = 0; ntl < 2; ntl++) {
          W0[ntl] = *(const f16x8*)&w1s[kts * 2048 + ntl * 1024 + lane * 8];
          W1[ntl] = *(const f16x8*)&w1s[kts * 2048 + ntl * 1024 + 512 + lane * 8];
          bb[ntl] = *(const f32x4*)(b1 + kts * 32 + ntl * 16 + q * 4);
        }
      }
      f16x8 Ba[4];                            // a1(kt), written last iteration
#pragma unroll
      for (int g = 0; g < 4; g++)
        Ba[g] = *(const f16x8*)&rep[w8][g][lane * 8];

      if (more) {
#pragma unroll
        for (int ntl = 0; ntl < 2; ntl++) {
          const int roff = ((2 * ntl + (q >> 1)) * 16 + c) * 8 + (q & 1) * 4;
#pragma unroll
          for (int g = 0; g < 4; g++) {
            f32x4 cc = __builtin_amdgcn_mfma_f32_16x16x32_f16(W0[ntl], Bs[g][0], bb[ntl], 0, 0, 0);
            cc = __builtin_amdgcn_mfma_f32_16x16x32_f16(W1[ntl], Bs[g][1], cc, 0, 0, 0);
            f16x4 pk;
#pragma unroll
            for (int r = 0; r < 4; r++)
              pk[r] = (_Float16)(cc[r] > 0.f ? cc[r] : 0.f);
            *(f16x4*)&rep[w8][g][roff] = pk;
          }
        }
      }

#pragma unroll
      for (int nt = 0; nt < 8; nt++)
#pragma unroll
        for (int g = 0; g < 4; g++)
          acc2[g][nt] = __builtin_amdgcn_mfma_f32_16x16x32_f16(A2[nt], Ba[g], acc2[g][nt], 0, 0, 0);
    }

    // ---- layer3: out[row] = sum relu(a2 + b2) * w3 + b3
    float part[4] = {0.f, 0.f, 0.f, 0.f};
#pragma unroll
    for (int nt = 0; nt < 8; nt++) {
      f32x4 bb = *(const f32x4*)(b2 + nt * 16 + q * 4);
      f32x4 ww = *(const f32x4*)(w3 + nt * 16 + q * 4);
#pragma unroll
      for (int g = 0; g < 4; g++) {
#pragma unroll
        for (int r = 0; r < 4; r++) {
          float v = acc2[g][nt][r] + bb[r];
          v = v > 0.f ? v : 0.f;
          part[g] = fmaf(v, ww[r], part[g]);
        }
      }
    }
#pragma unroll
    for (int g = 0; g < 4; g++) {
      part[g] += __shfl_xor(part[g], 16, 64);
      part[g] += __shfl_xor(part[g], 32, 64);
    }
    // lane (c,q) writes seq seqB+q, timestep ch*16+c
    float pv = (q == 0) ? part[0] : (q == 1) ? part[1] : (q == 2) ? part[2] : part[3];
    out[(size_t)(seqB + q) * Tdim + tB + c] = pv + b3[0];
  }
}

// ----------------------------------------------------------------
extern "C" void kernel_launch(void* const* d_in, const int* in_sizes, int n_in,
                              void* d_out, int out_size, void* d_ws, size_t ws_size,
                              hipStream_t stream) {
  const float* x    = (const float*)d_in[0];
  const float* W_ih = (const float*)d_in[1];
  const float* W_hh = (const float*)d_in[2];
  const float* b_ih = (const float*)d_in[3];
  const float* b_hh = (const float*)d_in[4];
  const float* w1   = (const float*)d_in[5];
  const float* b1   = (const float*)d_in[6];
  const float* w2   = (const float*)d_in[7];
  const float* b2   = (const float*)d_in[8];
  const float* w3   = (const float*)d_in[9];
  const float* b3   = (const float*)d_in[10];
  float* out = (float*)d_out;

  char* ws = (char*)d_ws;
  _Float16* sxf = (_Float16*)ws;                               // 52,428,800 B
  _Float16* Wf  = (_Float16*)(ws + 52428800);                  // 36,864 B
  _Float16* w1p = (_Float16*)(ws + 52428800 + 36864);          // 65,536 B
  _Float16* w2p = (_Float16*)(ws + 52428800 + 36864 + 65536);  // 131,072 B
  unsigned int* syncb = (unsigned int*)(ws + 52428800 + 36864 + 65536 + 131072); // 3,208 B
  unsigned int* flags  = syncb;        // [800]
  unsigned int* ticket = syncb + 800;  // [1]
  unsigned int* qhead  = syncb + 801;  // [1]

  hipLaunchKernelGGL(prep_kernel, dim3(456), dim3(256), 0, stream,
                     W_ih, W_hh, w1, w2, Wf, w1p, w2p, syncb);
  hipLaunchKernelGGL(fused_kernel, dim3(NGRU + NMLP), dim3(512), 0, stream,
                     x, Wf, b_ih, b_hh, sxf, w1p, w2p, b1, b2, w3, b3, out,
                     flags, ticket, qhead);
}

// Round 11
// 235.206 us; speedup vs baseline: 1.2655x; 1.0118x over previous
//
#include <hip/hip_runtime.h>
#include <stdint.h>

#define Tdim 128
#define Zdim 100
#define Sdim 6
#define Hdim 64
#define ZB   3200           // Z*B
#define F1   512
#define F2   128
#define Mrows (ZB * Tdim)   // 409600
#define NGRU 100            // gru-role blocks (ZB/32)
#define NMLP 800            // mlp-role blocks (NGRU * 8 chunks)
#define FSTRIDE 8           // flag padding: 32 B apart (2 per 64 B line, was 16)

typedef _Float16 f16x8 __attribute__((ext_vector_type(8)));
typedef _Float16 f16x4 __attribute__((ext_vector_type(4)));
typedef float f32x4 __attribute__((ext_vector_type(4)));
typedef uint32_t u32x4 __attribute__((ext_vector_type(4)));

__device__ __forceinline__ float fast_rcp(float x) {
  return __builtin_amdgcn_rcpf(x);   // v_rcp_f32: 1 trans op, no div-fixup chain
}

// ---------------------------------------------------------------- prep
// Wf[192][96] fp16: [W_hh | W_ih | 0] per gate (K=96 fused), for the GRU.
// w1p frag-linear: [kt][ntl][kfrag][lane][8].  32768 f16.
// w2p frag-linear: [kt][nt][lane][8].          65536 f16.
// Zeroes sync area: flags[800*FSTRIDE] + ticket + qhead, each iteration.
__global__ __launch_bounds__(256) void prep_kernel(
    const float* __restrict__ W_ih, const float* __restrict__ W_hh,
    const float* __restrict__ w1, const float* __restrict__ w2,
    _Float16* __restrict__ Wf, _Float16* __restrict__ w1p,
    _Float16* __restrict__ w2p, unsigned int* __restrict__ sync) {
  int i = blockIdx.x * 256 + threadIdx.x;     // grid covers 116736
  if (i < NMLP * FSTRIDE + 2) sync[i] = 0u;   // flags (padded) + ticket + qhead
  if (i < 192 * 96) {
    int g = i / 96, k = i - g * 96;
    float v = (k < 64) ? W_hh[g * 64 + k] : ((k < 70) ? W_ih[g * 6 + (k - 64)] : 0.f);
    Wf[i] = (_Float16)v;
  }
  int j = i - 192 * 96;
  if (j >= 0 && j < 32768) {
    int kt = j >> 11, ntl = (j >> 10) & 1, kf = (j >> 9) & 1;
    int lane = (j >> 3) & 63, e = j & 7;
    int q = lane >> 4, c = lane & 15;
    int row = kt * 32 + ntl * 16 + c;
    int h = kf * 32 + q * 8 + e;
    w1p[j] = (_Float16)w1[row * 64 + h];
  }
  int l = j - 32768;
  if (l >= 0 && l < 65536) {
    int kt = l >> 12, nt = (l >> 9) & 7;
    int lane = (l >> 3) & 63, e = l & 7;
    int q = lane >> 4, c = lane & 15;
    int row = nt * 16 + c;
    int k = kt * 32 + q * 8 + e;
    w2p[l] = (_Float16)w2[row * 512 + k];
  }
}

// ---------------------------------------------------------------- fused GRU+MLP
// (R10 structure; this round's ONLY changes: 32 B-padded flags + slower
// poll cadence, testing the poll/cacheline-contention hypothesis for the
// ~55 us gap between timeline arithmetic (~135) and measured (~191).)
// 900 blocks x 512 threads, 1 block/CU (LDS union ~139.3 KB).
// First 100 started blocks (ticket) take GRU with x preloaded in LDS;
// consumers claim items dynamically oldest-first via qhead.
__global__ __launch_bounds__(512, 2) void fused_kernel(
    const float* __restrict__ x, const _Float16* __restrict__ Wf,
    const float* __restrict__ b_ih, const float* __restrict__ b_hh,
    _Float16* __restrict__ sx, const _Float16* __restrict__ w1p,
    const _Float16* __restrict__ w2p, const float* __restrict__ b1,
    const float* __restrict__ b2, const float* __restrict__ w3,
    const float* __restrict__ b3, float* __restrict__ out,
    unsigned int* __restrict__ flags, unsigned int* __restrict__ ticket,
    unsigned int* __restrict__ qhead) {
  union SmemU {
    struct { _Float16 hist[16][32][72]; _Float16 xs[Tdim][32][8]; } g;  // 136 KB
    struct { _Float16 w1s[32768]; _Float16 rep[8][4][512]; } m;         // 96 KB
  };
  __shared__ __align__(16) SmemU smem;
  __shared__ int s_tk;
  const int tid = threadIdx.x;
  if (tid == 0) s_tk = (int)atomicAdd(ticket, 1u);
  __syncthreads();
  const int tk = s_tk;

  const int lane = tid & 63;
  const int w8 = tid >> 6;                    // wave id 0..7
  const int c = lane & 15;                    // MFMA col
  const int q = lane >> 4;                    // quad

  if (tk < NGRU) {
    // =============================== GRU role (proven R3) ===============
    const int gb = tk;
    auto& hist = smem.g.hist;
    auto& xs = smem.g.xs;
    const int s = w8 >> 2;                    // stream 0/1
    const int w = w8 & 3;                     // gate-tile wave within stream
    const int s16c = s * 16 + c;

    // ---- preload x for this block's 32 rows, pre-converted to fp16
    for (int i = 0; i < 8; i++) {
      int idx = i * 512 + tid;                // 0..4095 = (t, row)
      int t = idx >> 5, row = idx & 31;
      int nr = gb * 32 + row;                 // n = z*32 + b
      const float* p = x + (size_t)(nr & 31) * (Tdim * Zdim * Sdim)
                         + (size_t)t * (Zdim * Sdim) + (size_t)(nr >> 5) * Sdim;
      f16x8 v;
      v[0] = (_Float16)p[0]; v[1] = (_Float16)p[1]; v[2] = (_Float16)p[2];
      v[3] = (_Float16)p[3]; v[4] = (_Float16)p[4]; v[5] = (_Float16)p[5];
      v[6] = (_Float16)0.f;  v[7] = (_Float16)0.f;
      *(f16x8*)&xs[t][row][0] = v;
    }

    const int gr0 = w * 16;
    const int gz0 = 64 + w * 16;
    const int gn0 = 128 + w * 16;

    f16x8 Ar[3], Az[3], Anh[2], Ani;
#pragma unroll
    for (int kf = 0; kf < 3; kf++) {
      Ar[kf] = *(const f16x8*)(Wf + (size_t)(gr0 + c) * 96 + kf * 32 + q * 8);
      Az[kf] = *(const f16x8*)(Wf + (size_t)(gz0 + c) * 96 + kf * 32 + q * 8);
    }
    Anh[0] = *(const f16x8*)(Wf + (size_t)(gn0 + c) * 96 + q * 8);
    Anh[1] = *(const f16x8*)(Wf + (size_t)(gn0 + c) * 96 + 32 + q * 8);
    Ani    = *(const f16x8*)(Wf + (size_t)(gn0 + c) * 96 + 64 + q * 8);

    f32x4 Cr, Cz, Cnh, Cni;
    {
      f32x4 bir = *(const f32x4*)(b_ih + gr0 + q * 4);
      f32x4 bhr = *(const f32x4*)(b_hh + gr0 + q * 4);
      f32x4 biz = *(const f32x4*)(b_ih + gz0 + q * 4);
      f32x4 bhz = *(const f32x4*)(b_hh + gz0 + q * 4);
#pragma unroll
      for (int r = 0; r < 4; r++) { Cr[r] = bir[r] + bhr[r]; Cz[r] = biz[r] + bhz[r]; }
      Cnh = *(const f32x4*)(b_hh + gn0 + q * 4);
      Cni = *(const f32x4*)(b_ih + gn0 + q * 4);
    }

    const uint32_t xmask = (q == 0) ? 0xffffffffu : 0u;

    __syncthreads();                          // xs ready

    f16x8 Bh0 = {0, 0, 0, 0, 0, 0, 0, 0};
    f16x8 Bh1 = {0, 0, 0, 0, 0, 0, 0, 0};
    f32x4 hprev = {0.f, 0.f, 0.f, 0.f};

    f32x4 Dr_s, Dz_s, Dni_s;
    {
      u32x4 xv = *(const u32x4*)&xs[0][s16c][0];
      xv[0] &= xmask; xv[1] &= xmask; xv[2] &= xmask; xv[3] &= xmask;
      f16x8 Bx = *(f16x8*)&xv;
      Dni_s = __builtin_amdgcn_mfma_f32_16x16x32_f16(Ani, Bx, Cni, 0, 0, 0);
      Dr_s  = __builtin_amdgcn_mfma_f32_16x16x32_f16(Ar[2], Bx, Cr, 0, 0, 0);
      Dz_s  = __builtin_amdgcn_mfma_f32_16x16x32_f16(Az[2], Bx, Cz, 0, 0, 0);
    }

#pragma unroll 1
    for (int tch = 0; tch < 8; tch++) {
#pragma unroll 1
      for (int tc = 0; tc < 16; tc++) {
        const int t = tch * 16 + tc;
        f32x4 Dnh = __builtin_amdgcn_mfma_f32_16x16x32_f16(Anh[0], Bh0, Cnh, 0, 0, 0);
        f32x4 Dr  = __builtin_amdgcn_mfma_f32_16x16x32_f16(Ar[0], Bh0, Dr_s, 0, 0, 0);
        f32x4 Dz  = __builtin_amdgcn_mfma_f32_16x16x32_f16(Az[0], Bh0, Dz_s, 0, 0, 0);
        Dnh = __builtin_amdgcn_mfma_f32_16x16x32_f16(Anh[1], Bh1, Dnh, 0, 0, 0);
        Dr  = __builtin_amdgcn_mfma_f32_16x16x32_f16(Ar[1], Bh1, Dr, 0, 0, 0);
        Dz  = __builtin_amdgcn_mfma_f32_16x16x32_f16(Az[1], Bh1, Dz, 0, 0, 0);

        f16x4 pk;
#pragma unroll
        for (int r = 0; r < 4; r++) {
          float er = __expf(-Dr[r]);
          float rr = fast_rcp(1.f + er);
          float ez = __expf(-Dz[r]);
          float zg = fast_rcp(1.f + ez);
          float na = Dni_s[r] + rr * Dnh[r];
          float en = __expf(2.f * na);
          float nn = 1.f - 2.f * fast_rcp(en + 1.f);
          float hnew = nn + zg * (hprev[r] - nn);
          hprev[r] = hnew;
          pk[r] = (_Float16)hnew;
        }
        *(f16x4*)&hist[tc][s16c][w * 16 + q * 4] = pk;

        if (t + 1 < Tdim) {
          u32x4 xv = *(const u32x4*)&xs[t + 1][s16c][0];
          xv[0] &= xmask; xv[1] &= xmask; xv[2] &= xmask; xv[3] &= xmask;
          f16x8 Bx = *(f16x8*)&xv;
          Dni_s = __builtin_amdgcn_mfma_f32_16x16x32_f16(Ani, Bx, Cni, 0, 0, 0);
          Dr_s  = __builtin_amdgcn_mfma_f32_16x16x32_f16(Ar[2], Bx, Cr, 0, 0, 0);
          Dz_s  = __builtin_amdgcn_mfma_f32_16x16x32_f16(Az[2], Bx, Cz, 0, 0, 0);
        }
        __syncthreads();                      // h exchange across gate waves
        Bh0 = *(const f16x8*)&hist[tc][s16c][q * 8];
        Bh1 = *(const f16x8*)&hist[tc][s16c][32 + q * 8];
      }
      // coalesced dump of the 16-step chunk; wave w8 handles rows 4*w8..+3
      {
        const int t0 = tch * 16;
#pragma unroll
        for (int rr2 = 0; rr2 < 4; rr2++) {
          const int row = w8 * 4 + rr2;
          const int nrow = gb * 32 + row;
          _Float16* dst = sx + (size_t)nrow * Tdim * Hdim + (size_t)t0 * Hdim;
#pragma unroll
          for (int it = 0; it < 2; it++) {
            int idx = it * 64 + lane;         // 0..127
            int tcc = idx >> 3, hd8 = idx & 7;
            f16x8 vv = *(const f16x8*)&hist[tcc][row][hd8 * 8];
            *(f16x8*)(dst + tcc * 64 + hd8 * 8) = vv;
          }
        }
        __syncthreads();                      // dump drained (vmcnt 0) + hist reusable
        if (tid == 0) {
          __threadfence();                    // agent-scope: L2 writeback of sx
          atomicAdd(&flags[(gb * 8 + tch) * FSTRIDE], 1u);  // publish chunk
        }
      }
    }
  } else {
    // =============================== MLP role ===========================
    // Dynamic oldest-first claim: item = (ch = claim/100, gb = claim%100).
    __syncthreads();                          // everyone has read tk
    if (tid == 0) s_tk = (int)atomicAdd(qhead, 1u);
    __syncthreads();
    const int claim = s_tk;                   // 0..799
    const int ch  = claim / NGRU;             // chunk 0..7, oldest first
    const int gbm = claim % NGRU;             // producer gru block
    auto& w1s = smem.m.w1s;
    auto& rep = smem.m.rep;

    // ---- stage all of w1 into LDS while waiting (64 KB)
    {
      const u32x4* srcw = (const u32x4*)w1p;  // 4096 u32x4
      u32x4* dstw = (u32x4*)w1s;
#pragma unroll
      for (int i = 0; i < 8; i++)
        dstw[i * 512 + tid] = srcw[i * 512 + tid];
    }
    // ---- wait for producer chunk (slow-cadence poll: 16x less traffic)
    if (tid == 0) {
      while (__hip_atomic_load(&flags[(gbm * 8 + ch) * FSTRIDE], __ATOMIC_RELAXED,
                               __HIP_MEMORY_SCOPE_AGENT) == 0u)
        __builtin_amdgcn_s_sleep(32);
      (void)__hip_atomic_load(&flags[(gbm * 8 + ch) * FSTRIDE], __ATOMIC_ACQUIRE,
                              __HIP_MEMORY_SCOPE_AGENT);  // inv caches
    }
    __syncthreads();                          // flag seen + w1s ready

    // wave w8 owns 4 seqs x 16 timesteps: row(g,c) = (seqB+g)*128 + ch*16 + c
    const int seqB = gbm * 32 + w8 * 4;
    const size_t tB = (size_t)ch * 16;

    f16x8 Bs[4][2];
#pragma unroll
    for (int g = 0; g < 4; g++)
#pragma unroll
      for (int kk = 0; kk < 2; kk++)
        Bs[g][kk] = *(const f16x8*)(sx + ((size_t)(seqB + g) * Tdim + tB + c) * Hdim
                                    + kk * 32 + q * 8);

    f32x4 acc2[4][8];
#pragma unroll
    for (int g = 0; g < 4; g++)
#pragma unroll
      for (int nt = 0; nt < 8; nt++) acc2[g][nt] = (f32x4){0.f, 0.f, 0.f, 0.f};

    // ---- prologue: layer1 for kt=0 into rep
    {
#pragma unroll
      for (int ntl = 0; ntl < 2; ntl++) {
        f16x8 A0 = *(const f16x8*)&w1s[ntl * 1024 + lane * 8];
        f16x8 A1 = *(const f16x8*)&w1s[ntl * 1024 + 512 + lane * 8];
        f32x4 bb = *(const f32x4*)(b1 + ntl * 16 + q * 4);
        const int roff = ((2 * ntl + (q >> 1)) * 16 + c) * 8 + (q & 1) * 4;
#pragma unroll
        for (int g = 0; g < 4; g++) {
          f32x4 cc = __builtin_amdgcn_mfma_f32_16x16x32_f16(A0, Bs[g][0], bb, 0, 0, 0);
          cc = __builtin_amdgcn_mfma_f32_16x16x32_f16(A1, Bs[g][1], cc, 0, 0, 0);
          f16x4 pk;
#pragma unroll
          for (int r = 0; r < 4; r++)
            pk[r] = (_Float16)(cc[r] > 0.f ? cc[r] : 0.f);
          *(f16x4*)&rep[w8][g][roff] = pk;
        }
      }
    }

#pragma unroll 1
    for (int kt = 0; kt < 16; kt++) {
      const int ktn = kt + 1;
      const bool more = (ktn < 16);
      f16x8 A2[8];                            // layer2 weights for kt (global/L2)
#pragma unroll
      for (int nt = 0; nt < 8; nt++)
        A2[nt] = *(const f16x8*)(w2p + (size_t)kt * 4096 + nt * 512 + lane * 8);
      f16x8 W0[2], W1[2];                     // layer1 weights for kt+1 (LDS)
      f32x4 bb[2];
      {
        const int kts = more ? ktn : kt;
#pragma unroll
        for (int ntl = 0; ntl < 2; ntl++) {
          W0[ntl] = *(const f16x8*)&w1s[kts * 2048 + ntl * 1024 + lane * 8];
          W1[ntl] = *(const f16x8*)&w1s[kts * 2048 + ntl * 1024 + 512 + lane * 8];
          bb[ntl] = *(const f32x4*)(b1 + kts * 32 + ntl * 16 + q * 4);
        }
      }
      f16x8 Ba[4];                            // a1(kt), written last iteration
#pragma unroll
      for (int g = 0; g < 4; g++)
        Ba[g] = *(const f16x8*)&rep[w8][g][lane * 8];

      if (more) {
#pragma unroll
        for (int ntl = 0; ntl < 2; ntl++) {
          const int roff = ((2 * ntl + (q >> 1)) * 16 + c) * 8 + (q & 1) * 4;
#pragma unroll
          for (int g = 0; g < 4; g++) {
            f32x4 cc = __builtin_amdgcn_mfma_f32_16x16x32_f16(W0[ntl], Bs[g][0], bb[ntl], 0, 0, 0);
            cc = __builtin_amdgcn_mfma_f32_16x16x32_f16(W1[ntl], Bs[g][1], cc, 0, 0, 0);
            f16x4 pk;
#pragma unroll
            for (int r = 0; r < 4; r++)
              pk[r] = (_Float16)(cc[r] > 0.f ? cc[r] : 0.f);
            *(f16x4*)&rep[w8][g][roff] = pk;
          }
        }
      }

#pragma unroll
      for (int nt = 0; nt < 8; nt++)
#pragma unroll
        for (int g = 0; g < 4; g++)
          acc2[g][nt] = __builtin_amdgcn_mfma_f32_16x16x32_f16(A2[nt], Ba[g], acc2[g][nt], 0, 0, 0);
    }

    // ---- layer3: out[row] = sum relu(a2 + b2) * w3 + b3
    float part[4] = {0.f, 0.f, 0.f, 0.f};
#pragma unroll
    for (int nt = 0; nt < 8; nt++) {
      f32x4 bb = *(const f32x4*)(b2 + nt * 16 + q * 4);
      f32x4 ww = *(const f32x4*)(w3 + nt * 16 + q * 4);
#pragma unroll
      for (int g = 0; g < 4; g++) {
#pragma unroll
        for (int r = 0; r < 4; r++) {
          float v = acc2[g][nt][r] + bb[r];
          v = v > 0.f ? v : 0.f;
          part[g] = fmaf(v, ww[r], part[g]);
        }
      }
    }
#pragma unroll
    for (int g = 0; g < 4; g++) {
      part[g] += __shfl_xor(part[g], 16, 64);
      part[g] += __shfl_xor(part[g], 32, 64);
    }
    // lane (c,q) writes seq seqB+q, timestep ch*16+c
    float pv = (q == 0) ? part[0] : (q == 1) ? part[1] : (q == 2) ? part[2] : part[3];
    out[(size_t)(seqB + q) * Tdim + tB + c] = pv + b3[0];
  }
}

// ----------------------------------------------------------------
extern "C" void kernel_launch(void* const* d_in, const int* in_sizes, int n_in,
                              void* d_out, int out_size, void* d_ws, size_t ws_size,
                              hipStream_t stream) {
  const float* x    = (const float*)d_in[0];
  const float* W_ih = (const float*)d_in[1];
  const float* W_hh = (const float*)d_in[2];
  const float* b_ih = (const float*)d_in[3];
  const float* b_hh = (const float*)d_in[4];
  const float* w1   = (const float*)d_in[5];
  const float* b1   = (const float*)d_in[6];
  const float* w2   = (const float*)d_in[7];
  const float* b2   = (const float*)d_in[8];
  const float* w3   = (const float*)d_in[9];
  const float* b3   = (const float*)d_in[10];
  float* out = (float*)d_out;

  char* ws = (char*)d_ws;
  _Float16* sxf = (_Float16*)ws;                               // 52,428,800 B
  _Float16* Wf  = (_Float16*)(ws + 52428800);                  // 36,864 B
  _Float16* w1p = (_Float16*)(ws + 52428800 + 36864);          // 65,536 B
  _Float16* w2p = (_Float16*)(ws + 52428800 + 36864 + 65536);  // 131,072 B
  unsigned int* syncb = (unsigned int*)(ws + 52428800 + 36864 + 65536 + 131072); // 25,608 B
  unsigned int* flags  = syncb;                      // [800 * FSTRIDE], 32 B apart
  unsigned int* ticket = syncb + NMLP * FSTRIDE;     // [1]
  unsigned int* qhead  = syncb + NMLP * FSTRIDE + 1; // [1]

  hipLaunchKernelGGL(prep_kernel, dim3(456), dim3(256), 0, stream,
                     W_ih, W_hh, w1, w2, Wf, w1p, w2p, syncb);
  hipLaunchKernelGGL(fused_kernel, dim3(NGRU + NMLP), dim3(512), 0, stream,
                     x, Wf, b_ih, b_hh, sxf, w1p, w2p, b1, b2, w3, b3, out,
                     flags, ticket, qhead);
}